// Round 12
// baseline (97.566 us; speedup 1.0000x reference)
//
#include <hip/hip_runtime.h>

#define B_ 2
#define N_ 512
#define C_ 128   // HIDDEN_DIM
#define A_ 64    // ATTN_DIM
#define H_ 128

#define SC2L 2.885390081777927f     // 2*log2(e): exp(2x) = 2^(SC2L*x)
#define NEG2LE -2.885390081777927f  // -2*log2(e)

// workspace layout (float offsets)
#define OFF_WET 0                           // We^T [A][H] (8192)
#define OFF_V   (OFF_WET + A_*H_)           // v = exp(2 h_o) fp32 [g][a]
#define OFF_UT8 (OFF_V   + B_*N_*A_)        // u bf16 [b][a/8][n][8]
#define OFF_US8 (OFF_UT8 + B_*N_*A_/2)      // u bf16 [b][j/8][a][8]
#define OFF_XYP (OFF_US8 + B_*N_*A_/2)      // Xy bf16 pairs [b][j/2][h]

__device__ __forceinline__ float fexp2(float x) { return __builtin_amdgcn_exp2f(x); }
__device__ __forceinline__ float frcp(float x)  { return __builtin_amdgcn_rcpf(x); }
__device__ __forceinline__ unsigned f2bf(float x) {   // fp32 -> bf16 bits (RNE)
  unsigned u = __float_as_uint(x);
  return (u + 0x7fffu + ((u >> 16) & 1u)) >> 16;
}
__device__ __forceinline__ float bf_lo(unsigned d) { return __uint_as_float(d << 16); }
__device__ __forceinline__ float bf_hi(unsigned d) { return __uint_as_float(d & 0xffff0000u); }

// ---------------- kernel 1: projections -> v (fp32), u & Xy (bf16) --------
// 512 blocks x 256 threads, 2 rows/block. Reads RAW weights (L2-hot).
// Block 0 also transposes We [H][A] -> WeT [A][H].
__global__ __launch_bounds__(256) void proj_kernel(
    const float* __restrict__ X, const float* __restrict__ Wo,
    const float* __restrict__ W1, const float* __restrict__ Wy,
    const float* __restrict__ by, const float* __restrict__ We,
    float* __restrict__ ws) {
  __shared__ float xs[2*C_];
  int row0 = blockIdx.x * 2;            // even; both rows same batch
  int t = threadIdx.x;
  if (t < 2*C_) xs[t] = X[(size_t)row0*C_ + t];
  __syncthreads();

  const float* W;
  int col;
  if (t < 64)       { W = Wo + (size_t)t*C_;         col = t; }
  else if (t < 128) { W = W1 + (size_t)(t - 64)*C_;  col = t - 64; }
  else              { W = Wy + (size_t)(t - 128)*C_; col = t - 128; }

  const float4* w4 = (const float4*)W;
  const float4* xA = (const float4*)xs;
  const float4* xB = (const float4*)(xs + C_);
  float acc0 = 0.f, acc1 = 0.f;
  #pragma unroll 8
  for (int k = 0; k < C_/4; ++k) {
    float4 wv = w4[k];
    float4 xa = xA[k], xb = xB[k];
    acc0 = fmaf(wv.x, xa.x, acc0); acc1 = fmaf(wv.x, xb.x, acc1);
    acc0 = fmaf(wv.y, xa.y, acc0); acc1 = fmaf(wv.y, xb.y, acc1);
    acc0 = fmaf(wv.z, xa.z, acc0); acc1 = fmaf(wv.z, xb.z, acc1);
    acc0 = fmaf(wv.w, xa.w, acc0); acc1 = fmaf(wv.w, xb.w, acc1);
  }

  int b = row0 >> 9, n0 = row0 & (N_-1);

  if (t < 64) {                         // v = exp(2 h_o), fp32
    float* o = ws + OFF_V + (size_t)row0*A_ + col;
    o[0] = fexp2(SC2L * acc0);
    o[A_] = fexp2(SC2L * acc1);
  } else if (t < 128) {                 // u = exp(2 h_1), bf16, two layouts
    int a = col;
    unsigned u0 = f2bf(fexp2(SC2L * acc0));
    unsigned u1 = f2bf(fexp2(SC2L * acc1));
    unsigned short* ut = (unsigned short*)(ws + OFF_UT8);
    size_t bA = ((size_t)(b*8 + (a >> 3))*N_ + n0)*8 + (a & 7);
    ut[bA] = (unsigned short)u0;
    ut[bA + 8] = (unsigned short)u1;
    unsigned short* us = (unsigned short*)(ws + OFF_US8);
    size_t bC = ((size_t)(b*64 + (n0 >> 3))*A_ + a)*8 + (n0 & 7);
    us[bC] = (unsigned short)u0;
    us[bC + 1] = (unsigned short)u1;
  } else {                              // Xy bf16 pairs [b][k][h]
    int h = col;
    float bb = by[h];
    unsigned xv0 = f2bf(acc0 + bb);
    unsigned xv1 = f2bf(acc1 + bb);
    unsigned* xp = (unsigned*)(ws + OFF_XYP);
    xp[(size_t)(b*(N_/2) + (n0 >> 1))*H_ + h] = xv0 | (xv1 << 16);
  }

  if (blockIdx.x == 0) {                // WeT [A][H]
    for (int k = t; k < A_*H_; k += 256) {
      int h = k >> 6, a = k & 63;
      ws[OFF_WET + a*H_ + h] = We[k];
    }
  }
}

// ---------------- kernel 2: attention, TI=1, dwordx4 bf16 streams ---------
// 1024 blocks x 512 threads = 4 blocks/CU target, 32 waves/CU.
__global__ __launch_bounds__(512) void attn_kernel(
    const float* __restrict__ Wphi, const float* __restrict__ be,
    const float* __restrict__ ws, float* __restrict__ out) {
  __shared__ __align__(16) float pkv[A_];   // v_a
  __shared__ __align__(16) float pkw[A_];   // wphi_a
  __shared__ float sc[N_];                  // p_j
  __shared__ float reds[8];
  __shared__ float ebw[8][A_];
  __shared__ float ebar[A_];
  __shared__ __align__(16) float p1s[16][H_];

  int t = threadIdx.x;
  int w = t >> 6, lane = t & 63;
  int bi = blockIdx.x;                      // global row
  int b = bi >> 9, i = bi & (N_-1);

  const uint4* ut8 = (const uint4*)((const unsigned short*)(ws + OFF_UT8))
                     + (size_t)b*8*N_;      // element [g][n]
  const uint4* us8 = (const uint4*)((const unsigned short*)(ws + OFF_US8))
                     + (size_t)b*64*A_;     // element [o][a]
  const uint4* xy4 = (const uint4*)((const unsigned*)(ws + OFF_XYP))
                     + (size_t)b*(N_/2)*(H_/4);  // element [k][h4]
  const float* wet = ws + OFF_WET;

  if (t < A_) {
    pkv[t] = ws[OFF_V + (size_t)(b*N_ + i)*A_ + t];
    pkw[t] = Wphi[t];
  }
  __syncthreads();

  // ---- Pass A: thread owns j = t; 8 x dwordx4 loads (8 a's each)
  float s = 0.f;
  {
    const float4* pv4 = (const float4*)pkv;
    const float4* pw4 = (const float4*)pkw;
    #pragma unroll
    for (int g = 0; g < 8; ++g) {
      uint4 d = ut8[(size_t)g*N_ + t];
      float4 v0 = pv4[2*g], v1 = pv4[2*g + 1];
      float4 w0 = pw4[2*g], w1 = pw4[2*g + 1];
      s = fmaf(w0.x, frcp(fmaf(v0.x, bf_lo(d.x), 1.f)), s);
      s = fmaf(w0.y, frcp(fmaf(v0.y, bf_hi(d.x), 1.f)), s);
      s = fmaf(w0.z, frcp(fmaf(v0.z, bf_lo(d.y), 1.f)), s);
      s = fmaf(w0.w, frcp(fmaf(v0.w, bf_hi(d.y), 1.f)), s);
      s = fmaf(w1.x, frcp(fmaf(v1.x, bf_lo(d.z), 1.f)), s);
      s = fmaf(w1.y, frcp(fmaf(v1.y, bf_hi(d.z), 1.f)), s);
      s = fmaf(w1.z, frcp(fmaf(v1.z, bf_lo(d.w), 1.f)), s);
      s = fmaf(w1.w, frcp(fmaf(v1.w, bf_hi(d.w), 1.f)), s);
    }
  }
  float p = fexp2(NEG2LE * s);              // shift-free softmax numerator
  sc[t] = p;
  float q = p;
  #pragma unroll
  for (int m = 1; m < 64; m <<= 1) q += __shfl_xor(q, m);
  if (lane == 0) reds[w] = q;
  __syncthreads();

  // ---- Pass C: lane = a; wave w covers j-octets o = oo*8 + w
  {
    float v = pkv[lane];
    const float4* sc4 = (const float4*)sc;
    float c = 0.f;
    #pragma unroll
    for (int oo = 0; oo < 8; ++oo) {
      int o = oo*8 + w;
      uint4 d = us8[(size_t)o*A_ + lane];
      float4 pA = sc4[o*2], pB = sc4[o*2 + 1];
      c = fmaf(pA.x, frcp(fmaf(v, bf_lo(d.x), 1.f)), c);
      c = fmaf(pA.y, frcp(fmaf(v, bf_hi(d.x), 1.f)), c);
      c = fmaf(pA.z, frcp(fmaf(v, bf_lo(d.y), 1.f)), c);
      c = fmaf(pA.w, frcp(fmaf(v, bf_hi(d.y), 1.f)), c);
      c = fmaf(pB.x, frcp(fmaf(v, bf_lo(d.z), 1.f)), c);
      c = fmaf(pB.y, frcp(fmaf(v, bf_hi(d.z), 1.f)), c);
      c = fmaf(pB.z, frcp(fmaf(v, bf_lo(d.w), 1.f)), c);
      c = fmaf(pB.w, frcp(fmaf(v, bf_hi(d.w), 1.f)), c);
    }
    ebw[w][lane] = c;
  }

  // ---- part1: thread = (qd = t>>5, h4 = t&31); 16 x dwordx4 (4 h-pairs)
  {
    int h4 = t & 31, qd = t >> 5;
    float d0 = 0.f, d1 = 0.f, d2 = 0.f, d3 = 0.f;
    #pragma unroll
    for (int kc = 0; kc < 16; ++kc) {
      int k = qd*16 + kc;
      uint4 d = xy4[(size_t)k*(H_/4) + h4];
      float pa = sc[2*k], pb = sc[2*k + 1];
      d0 = fmaf(pa, bf_lo(d.x), d0); d0 = fmaf(pb, bf_hi(d.x), d0);
      d1 = fmaf(pa, bf_lo(d.y), d1); d1 = fmaf(pb, bf_hi(d.y), d1);
      d2 = fmaf(pa, bf_lo(d.z), d2); d2 = fmaf(pb, bf_hi(d.z), d2);
      d3 = fmaf(pa, bf_lo(d.w), d3); d3 = fmaf(pb, bf_hi(d.w), d3);
    }
    *(float4*)&p1s[qd][h4*4] = make_float4(d0, d1, d2, d3);
  }
  __syncthreads();

  // ---- reduce ebar: ebar_un[a] = l - 2*sum_w ebw[w][a]
  if (t < A_) {
    float e = 0.f;
    #pragma unroll
    for (int k = 0; k < 8; ++k) e += ebw[k][t];
    float l = 0.f;
    #pragma unroll
    for (int k = 0; k < 8; ++k) l += reds[k];
    ebar[t] = l - 2.0f*e;
  }
  __syncthreads();

  // ---- epilogue: out = (part1_un + We^T·ebar_un)/l + be
  if (t < H_) {
    int h = t;
    float l = 0.f;
    #pragma unroll
    for (int k = 0; k < 8; ++k) l += reds[k];
    float acc = 0.f;
    #pragma unroll
    for (int k = 0; k < 16; ++k) acc += p1s[k][h];
    float e2 = 0.f;
    #pragma unroll 8
    for (int a = 0; a < A_; ++a) e2 = fmaf(ebar[a], wet[a*H_ + h], e2);
    out[(size_t)bi*H_ + h] = (acc + e2) * frcp(l) + be[h];
  }
}

extern "C" void kernel_launch(void* const* d_in, const int* in_sizes, int n_in,
                              void* d_out, int out_size, void* d_ws, size_t ws_size,
                              hipStream_t stream) {
  const float* X    = (const float*)d_in[0];
  const float* Wo   = (const float*)d_in[1];
  const float* W1   = (const float*)d_in[2];
  const float* Wphi = (const float*)d_in[3];
  const float* Wy   = (const float*)d_in[4];
  const float* by   = (const float*)d_in[5];
  const float* We   = (const float*)d_in[6];
  const float* be   = (const float*)d_in[7];
  float* out = (float*)d_out;
  float* ws  = (float*)d_ws;

  hipLaunchKernelGGL(proj_kernel, dim3(B_*N_/2), dim3(256), 0, stream,
                     X, Wo, W1, Wy, by, We, ws);
  hipLaunchKernelGGL(attn_kernel, dim3(B_*N_), dim3(512), 0, stream,
                     Wphi, be, ws, out);
}

// Round 13
// 92.164 us; speedup vs baseline: 1.0586x; 1.0586x over previous
//
#include <hip/hip_runtime.h>

#define B_ 2
#define N_ 512
#define C_ 128   // HIDDEN_DIM
#define A_ 64    // ATTN_DIM
#define H_ 128

#define SC2L 2.885390081777927f     // 2*log2(e): exp(2x) = 2^(SC2L*x)
#define NEG2LE -2.885390081777927f  // -2*log2(e)

// workspace layout (float offsets)
#define OFF_WOT 0                           // Wo^T [C][A]
#define OFF_W1T (OFF_WOT + C_*A_)           // W1^T [C][A]
#define OFF_WYT (OFF_W1T + C_*A_)           // Wy^T [C][H]
#define OFF_WET (OFF_WYT + C_*H_)           // We^T [A][H]
#define OFF_V   (OFF_WET + A_*H_)           // v = exp(2 h_o) fp32 [g][a]
#define OFF_UT8 (OFF_V   + B_*N_*A_)        // u bf16 [b][a/8][n][8]
#define OFF_US8 (OFF_UT8 + B_*N_*A_/2)      // u bf16 [b][j/8][a][8]
#define OFF_XYP (OFF_US8 + B_*N_*A_/2)      // Xy bf16 pairs [b][j/2][h]

__device__ __forceinline__ float fexp2(float x) { return __builtin_amdgcn_exp2f(x); }
__device__ __forceinline__ float frcp(float x)  { return __builtin_amdgcn_rcpf(x); }
__device__ __forceinline__ unsigned f2bf(float x) {   // fp32 -> bf16 bits (RNE)
  unsigned u = __float_as_uint(x);
  return (u + 0x7fffu + ((u >> 16) & 1u)) >> 16;
}
__device__ __forceinline__ float bf_lo(unsigned d) { return __uint_as_float(d << 16); }
__device__ __forceinline__ float bf_hi(unsigned d) { return __uint_as_float(d & 0xffff0000u); }

// ---------------- kernel 0: transpose weights into ws ----------------
__global__ __launch_bounds__(256) void prep_weights(
    const float* __restrict__ Wo, const float* __restrict__ W1,
    const float* __restrict__ Wy, const float* __restrict__ We,
    float* __restrict__ ws) {
  int t = blockIdx.x * 256 + threadIdx.x;   // 0..16383
  if (t < A_*C_) {
    int a = t / C_, c = t % C_;
    ws[OFF_WOT + c*A_ + a] = Wo[t];
    ws[OFF_W1T + c*A_ + a] = W1[t];
    int h2 = t / A_, a2 = t % A_;
    ws[OFF_WET + a2*H_ + h2] = We[t];
  }
  if (t < H_*C_) {
    int h = t / C_, c = t % C_;
    ws[OFF_WYT + c*H_ + h] = Wy[t];
  }
}

// ---------------- kernel 1: projections -> v (fp32), u & Xy (bf16) --------
// 512 blocks x 256 threads, 2 rows/block; coalesced transposed-weight reads.
__global__ __launch_bounds__(256) void proj_kernel(
    const float* __restrict__ X, const float* __restrict__ by,
    float* __restrict__ ws) {
  __shared__ float xs[2*C_];
  int row0 = blockIdx.x * 2;            // even; both rows same batch
  int t = threadIdx.x;
  if (t < 2*C_) xs[t] = X[(size_t)row0*C_ + t];
  __syncthreads();

  const float* wt;
  int col, stride;
  if (t < 64)       { wt = ws + OFF_WOT; col = t;       stride = A_; }
  else if (t < 128) { wt = ws + OFF_W1T; col = t - 64;  stride = A_; }
  else              { wt = ws + OFF_WYT; col = t - 128; stride = H_; }

  float acc0 = 0.f, acc1 = 0.f;
  #pragma unroll 8
  for (int c = 0; c < C_; ++c) {
    float wv = wt[c*stride + col];
    acc0 = fmaf(xs[c], wv, acc0);
    acc1 = fmaf(xs[C_ + c], wv, acc1);
  }

  int b = row0 >> 9, n0 = row0 & (N_-1);

  if (t < 64) {                         // v = exp(2 h_o), fp32
    float* o = ws + OFF_V + (size_t)row0*A_ + col;
    o[0] = fexp2(SC2L * acc0);
    o[A_] = fexp2(SC2L * acc1);
  } else if (t < 128) {                 // u = exp(2 h_1), bf16, two layouts
    int a = col;
    unsigned u0 = f2bf(fexp2(SC2L * acc0));
    unsigned u1 = f2bf(fexp2(SC2L * acc1));
    unsigned short* ut = (unsigned short*)(ws + OFF_UT8);
    size_t bA = ((size_t)(b*8 + (a >> 3))*N_ + n0)*8 + (a & 7);
    ut[bA] = (unsigned short)u0;
    ut[bA + 8] = (unsigned short)u1;
    unsigned short* us = (unsigned short*)(ws + OFF_US8);
    size_t bC = ((size_t)(b*64 + (n0 >> 3))*A_ + a)*8 + (n0 & 7);
    us[bC] = (unsigned short)u0;
    us[bC + 1] = (unsigned short)u1;
  } else {                              // Xy bf16 pairs [b][k][h]
    int h = col;
    float bb = by[h];
    unsigned xv0 = f2bf(acc0 + bb);
    unsigned xv1 = f2bf(acc1 + bb);
    unsigned* xp = (unsigned*)(ws + OFF_XYP);
    xp[(size_t)(b*(N_/2) + (n0 >> 1))*H_ + h] = xv0 | (xv1 << 16);
  }
}

// ---------------- kernel 2: attention, TI=2, 1024 threads ----------------
// 512 blocks x 1024 threads (16 waves) = 2 blocks/CU, 32 waves/CU.
// Thread = (r, j) in Pass A (R10-lean registers); loads shared across rows.
__global__ __launch_bounds__(1024) void attn_kernel(
    const float* __restrict__ Wphi, const float* __restrict__ be,
    const float* __restrict__ ws, float* __restrict__ out) {
  __shared__ __align__(16) float pkv[2][A_]; // v rows
  __shared__ __align__(16) float pkw[A_];    // wphi
  __shared__ float sc[2][N_];                // p_j per row (4 KB)
  __shared__ float reds[16];                 // per-wave denom partials
  __shared__ float ebw[2][16][A_];           // ebar partials (8 KB)
  __shared__ float ebar[2][A_];
  __shared__ __align__(16) float p1s[2][32][H_];  // part1 partials (32 KB)

  int t = threadIdx.x;
  int w = t >> 6, lane = t & 63;
  int blk = blockIdx.x;                      // 0..511
  int b = blk >> 8;
  int i0 = (blk & 255) * 2;
  int g0 = b*N_ + i0;

  const uint4* ut8 = (const uint4*)((const unsigned short*)(ws + OFF_UT8))
                     + (size_t)b*8*N_;
  const uint4* us8 = (const uint4*)((const unsigned short*)(ws + OFF_US8))
                     + (size_t)b*64*A_;
  const uint4* xy4 = (const uint4*)((const unsigned*)(ws + OFF_XYP))
                     + (size_t)b*(N_/2)*(H_/4);
  const float* wet = ws + OFF_WET;

  if (t < 2*A_) {
    int r = t >> 6, a = t & 63;
    pkv[r][a] = ws[OFF_V + (size_t)(g0 + r)*A_ + a];
  } else if (t < 3*A_) {
    pkw[t - 2*A_] = Wphi[t - 2*A_];
  }
  __syncthreads();

  // ---- Pass A: thread = (r = t>>9, j = t&511); 8 x dwordx4 loads
  {
    int r = t >> 9, j = t & 511;
    const float4* pv4 = (const float4*)pkv[r];
    const float4* pw4 = (const float4*)pkw;
    float s = 0.f;
    #pragma unroll
    for (int g = 0; g < 8; ++g) {
      uint4 d = ut8[(size_t)g*N_ + j];
      float4 v0 = pv4[2*g], v1 = pv4[2*g + 1];
      float4 w0 = pw4[2*g], w1 = pw4[2*g + 1];
      s = fmaf(w0.x, frcp(fmaf(v0.x, bf_lo(d.x), 1.f)), s);
      s = fmaf(w0.y, frcp(fmaf(v0.y, bf_hi(d.x), 1.f)), s);
      s = fmaf(w0.z, frcp(fmaf(v0.z, bf_lo(d.y), 1.f)), s);
      s = fmaf(w0.w, frcp(fmaf(v0.w, bf_hi(d.y), 1.f)), s);
      s = fmaf(w1.x, frcp(fmaf(v1.x, bf_lo(d.z), 1.f)), s);
      s = fmaf(w1.y, frcp(fmaf(v1.y, bf_hi(d.z), 1.f)), s);
      s = fmaf(w1.z, frcp(fmaf(v1.z, bf_lo(d.w), 1.f)), s);
      s = fmaf(w1.w, frcp(fmaf(v1.w, bf_hi(d.w), 1.f)), s);
    }
    float p = fexp2(NEG2LE * s);             // shift-free softmax numerator
    sc[r][j] = p;
    float q = p;
    #pragma unroll
    for (int m = 1; m < 64; m <<= 1) q += __shfl_xor(q, m);
    if (lane == 0) reds[w] = q;              // waves 0-7 row0, 8-15 row1
  }
  __syncthreads();

  // ---- Pass C: lane = a; wave w covers octets o = oo*16 + w, both rows
  {
    float v0 = pkv[0][lane], v1 = pkv[1][lane];
    const float4* s40 = (const float4*)sc[0];
    const float4* s41 = (const float4*)sc[1];
    float c0 = 0.f, c1 = 0.f;
    #pragma unroll
    for (int oo = 0; oo < 4; ++oo) {
      int o = oo*16 + w;
      uint4 d = us8[(size_t)o*A_ + lane];
      float u0 = bf_lo(d.x), u1 = bf_hi(d.x), u2 = bf_lo(d.y), u3 = bf_hi(d.y);
      float u4 = bf_lo(d.z), u5 = bf_hi(d.z), u6 = bf_lo(d.w), u7 = bf_hi(d.w);
      float4 pA0 = s40[o*2], pB0 = s40[o*2 + 1];
      float4 pA1 = s41[o*2], pB1 = s41[o*2 + 1];
      float r0 = frcp(fmaf(v0, u0, 1.f)), q0 = frcp(fmaf(v1, u0, 1.f));
      float r1 = frcp(fmaf(v0, u1, 1.f)), q1 = frcp(fmaf(v1, u1, 1.f));
      float r2 = frcp(fmaf(v0, u2, 1.f)), q2 = frcp(fmaf(v1, u2, 1.f));
      float r3 = frcp(fmaf(v0, u3, 1.f)), q3 = frcp(fmaf(v1, u3, 1.f));
      float r4 = frcp(fmaf(v0, u4, 1.f)), q4 = frcp(fmaf(v1, u4, 1.f));
      float r5 = frcp(fmaf(v0, u5, 1.f)), q5 = frcp(fmaf(v1, u5, 1.f));
      float r6 = frcp(fmaf(v0, u6, 1.f)), q6 = frcp(fmaf(v1, u6, 1.f));
      float r7 = frcp(fmaf(v0, u7, 1.f)), q7 = frcp(fmaf(v1, u7, 1.f));
      c0 = fmaf(pA0.x, r0, c0); c1 = fmaf(pA1.x, q0, c1);
      c0 = fmaf(pA0.y, r1, c0); c1 = fmaf(pA1.y, q1, c1);
      c0 = fmaf(pA0.z, r2, c0); c1 = fmaf(pA1.z, q2, c1);
      c0 = fmaf(pA0.w, r3, c0); c1 = fmaf(pA1.w, q3, c1);
      c0 = fmaf(pB0.x, r4, c0); c1 = fmaf(pB1.x, q4, c1);
      c0 = fmaf(pB0.y, r5, c0); c1 = fmaf(pB1.y, q5, c1);
      c0 = fmaf(pB0.z, r6, c0); c1 = fmaf(pB1.z, q6, c1);
      c0 = fmaf(pB0.w, r7, c0); c1 = fmaf(pB1.w, q7, c1);
    }
    ebw[0][w][lane] = c0;
    ebw[1][w][lane] = c1;
  }

  // ---- part1: thread = (qd = t>>5 in [0,32), h4 = t&31); 8 xy4 loads, both rows
  {
    int h4 = t & 31, qd = t >> 5;
    float d0 = 0.f, d1 = 0.f, d2 = 0.f, d3 = 0.f;
    float e0 = 0.f, e1 = 0.f, e2 = 0.f, e3 = 0.f;
    const float2* p20 = (const float2*)sc[0];
    const float2* p21 = (const float2*)sc[1];
    #pragma unroll
    for (int kc = 0; kc < 8; ++kc) {
      int k = qd*8 + kc;
      uint4 d = xy4[(size_t)k*(H_/4) + h4];
      float2 P0 = p20[k];
      float2 P1 = p21[k];
      float xa = bf_lo(d.x), xb = bf_hi(d.x);
      float xc = bf_lo(d.y), xd = bf_hi(d.y);
      float xe = bf_lo(d.z), xf = bf_hi(d.z);
      float xg = bf_lo(d.w), xh = bf_hi(d.w);
      d0 = fmaf(P0.x, xa, d0); d0 = fmaf(P0.y, xb, d0);
      d1 = fmaf(P0.x, xc, d1); d1 = fmaf(P0.y, xd, d1);
      d2 = fmaf(P0.x, xe, d2); d2 = fmaf(P0.y, xf, d2);
      d3 = fmaf(P0.x, xg, d3); d3 = fmaf(P0.y, xh, d3);
      e0 = fmaf(P1.x, xa, e0); e0 = fmaf(P1.y, xb, e0);
      e1 = fmaf(P1.x, xc, e1); e1 = fmaf(P1.y, xd, e1);
      e2 = fmaf(P1.x, xe, e2); e2 = fmaf(P1.y, xf, e2);
      e3 = fmaf(P1.x, xg, e3); e3 = fmaf(P1.y, xh, e3);
    }
    *(float4*)&p1s[0][qd][h4*4] = make_float4(d0, d1, d2, d3);
    *(float4*)&p1s[1][qd][h4*4] = make_float4(e0, e1, e2, e3);
  }
  __syncthreads();

  // ---- reduce ebar: ebar_un[r][a] = l_r - 2*sum_w ebw[r][w][a]
  if (t < 2*A_) {
    int r = t >> 6, a = t & 63;
    float e = 0.f;
    #pragma unroll
    for (int k = 0; k < 16; ++k) e += ebw[r][k][a];
    float l = 0.f;
    #pragma unroll
    for (int k = 0; k < 8; ++k) l += reds[r*8 + k];
    ebar[r][a] = l - 2.0f*e;
  }
  __syncthreads();

  // ---- epilogue: out = (part1_un + We^T·ebar_un)/l + be
  if (t < 2*H_) {
    int r = t >> 7, h = t & 127;
    float l = 0.f;
    #pragma unroll
    for (int k = 0; k < 8; ++k) l += reds[r*8 + k];
    float acc = 0.f;
    #pragma unroll
    for (int k = 0; k < 32; ++k) acc += p1s[r][k][h];
    float e2 = 0.f;
    #pragma unroll 8
    for (int a = 0; a < A_; ++a) e2 = fmaf(ebar[r][a], wet[a*H_ + h], e2);
    out[(size_t)(g0 + r)*H_ + h] = (acc + e2) * frcp(l) + be[h];
  }
}

extern "C" void kernel_launch(void* const* d_in, const int* in_sizes, int n_in,
                              void* d_out, int out_size, void* d_ws, size_t ws_size,
                              hipStream_t stream) {
  const float* X    = (const float*)d_in[0];
  const float* Wo   = (const float*)d_in[1];
  const float* W1   = (const float*)d_in[2];
  const float* Wphi = (const float*)d_in[3];
  const float* Wy   = (const float*)d_in[4];
  const float* by   = (const float*)d_in[5];
  const float* We   = (const float*)d_in[6];
  const float* be   = (const float*)d_in[7];
  float* out = (float*)d_out;
  float* ws  = (float*)d_ws;

  hipLaunchKernelGGL(prep_weights, dim3(64), dim3(256), 0, stream, Wo, W1, Wy, We, ws);
  hipLaunchKernelGGL(proj_kernel, dim3(B_*N_/2), dim3(256), 0, stream, X, by, ws);
  hipLaunchKernelGGL(attn_kernel, dim3(B_*N_/2), dim3(1024), 0, stream, Wphi, be, ws, out);
}